// Round 1
// baseline (646.519 us; speedup 1.0000x reference)
//
#include <hip/hip_runtime.h>
#include <math.h>

// ---------- helpers ----------
__device__ __forceinline__ unsigned bf16b(float f) {
  unsigned u = __float_as_uint(f);
  return (u + 0x7fffu + ((u >> 16) & 1u)) >> 16;   // RNE
}
__device__ __forceinline__ unsigned packbf(float lo, float hi) {
  return bf16b(lo) | (bf16b(hi) << 16);
}
__device__ __forceinline__ float unpk_lo(unsigned u) { return __uint_as_float(u << 16); }
__device__ __forceinline__ float unpk_hi(unsigned u) { return __uint_as_float(u & 0xffff0000u); }
__device__ __forceinline__ float fcomp(const float4& v, int i) {
  switch (i) { case 0: return v.x; case 1: return v.y; case 2: return v.z; default: return v.w; }
}
__device__ __forceinline__ unsigned ucomp(const uint4& v, int i) {
  switch (i) { case 0: return v.x; case 1: return v.y; case 2: return v.z; default: return v.w; }
}
__device__ __forceinline__ float gelu_f(float v) {
  return 0.5f * v * (1.0f + erff(v * 0.70710678118654752f));
}

// ---------- fused LN1 + [Wl|Wr] GEMM, writes packed-bf16 xl/xr ----------
// pack layout: pk[i*64 + j] holds channels (2j, 2j+1) of row i
__global__ __launch_bounds__(256) void k_gemlr(
    const float* __restrict__ x, const float* __restrict__ ln1w,
    const float* __restrict__ Wl, const float* __restrict__ bl,
    const float* __restrict__ Wr, const float* __restrict__ br,
    unsigned* __restrict__ xlp, unsigned* __restrict__ xrp, int n)
{
  __shared__ float As[32 * 128];              // 16 KB
  const int t = threadIdx.x;
  const int r0 = blockIdx.x * 32;

  { // stage x tile (32 rows x 128 cols)
    const float4* xs = (const float4*)x;
    #pragma unroll
    for (int j = 0; j < 4; ++j) {
      int f = j * 256 + t;
      int row = f >> 5;
      int gr = r0 + row;
      float4 v = make_float4(0.f, 0.f, 0.f, 0.f);
      if (gr < n) v = xs[(size_t)gr * 32 + (f & 31)];
      ((float4*)As)[f] = v;
    }
  }
  __syncthreads();
  { // fused LayerNorm: 8 threads per row, 16 cols each
    const int row = t >> 3, seg = t & 7;
    float4 v[4];
    #pragma unroll
    for (int j = 0; j < 4; ++j) v[j] = ((float4*)As)[row * 32 + seg * 4 + j];
    float s = 0.f;
    #pragma unroll
    for (int j = 0; j < 4; ++j) s += v[j].x + v[j].y + v[j].z + v[j].w;
    s += __shfl_xor(s, 1); s += __shfl_xor(s, 2); s += __shfl_xor(s, 4);
    const float mean = s * (1.0f / 128.0f);
    float vv = 0.f;
    #pragma unroll
    for (int j = 0; j < 4; ++j) {
      float a = v[j].x - mean, b = v[j].y - mean, c = v[j].z - mean, d = v[j].w - mean;
      vv += a * a + b * b + c * c + d * d;
    }
    vv += __shfl_xor(vv, 1); vv += __shfl_xor(vv, 2); vv += __shfl_xor(vv, 4);
    const float rstd = rsqrtf(vv * (1.0f / 128.0f) + 1e-5f);
    #pragma unroll
    for (int j = 0; j < 4; ++j) {
      float4 w4 = ((const float4*)ln1w)[seg * 4 + j];
      float4 o;
      o.x = (v[j].x - mean) * rstd * w4.x;
      o.y = (v[j].y - mean) * rstd * w4.y;
      o.z = (v[j].z - mean) * rstd * w4.z;
      o.w = (v[j].w - mean) * rstd * w4.w;
      ((float4*)As)[row * 32 + seg * 4 + j] = o;
    }
  }
  __syncthreads();

  // GEMM: out[32][256] = h @ [Wl|Wr]; thread: 4 rows x 8 cols
  const int tx = t & 31, ty = t >> 5;
  const float* __restrict__ Wh = (tx < 16) ? Wl : Wr;
  const int c0 = (tx & 15) * 8;
  float acc[4][8];
  #pragma unroll
  for (int r = 0; r < 4; ++r) {
    #pragma unroll
    for (int j = 0; j < 8; ++j) acc[r][j] = 0.f;
  }
  for (int k = 0; k < 128; k += 4) {
    float4 a4[4];
    #pragma unroll
    for (int r = 0; r < 4; ++r)
      a4[r] = *(const float4*)&As[(ty * 4 + r) * 128 + k];
    #pragma unroll
    for (int kk = 0; kk < 4; ++kk) {
      const float* wrow = Wh + (size_t)(k + kk) * 128 + c0;
      const float4 b0 = *(const float4*)wrow;
      const float4 b1 = *(const float4*)(wrow + 4);
      #pragma unroll
      for (int r = 0; r < 4; ++r) {
        const float a = fcomp(a4[r], kk);
        acc[r][0] += a * b0.x; acc[r][1] += a * b0.y;
        acc[r][2] += a * b0.z; acc[r][3] += a * b0.w;
        acc[r][4] += a * b1.x; acc[r][5] += a * b1.y;
        acc[r][6] += a * b1.z; acc[r][7] += a * b1.w;
      }
    }
  }
  const float* __restrict__ bias = (tx < 16) ? bl : br;
  unsigned* __restrict__ outp = (tx < 16) ? xlp : xrp;
  float b8[8];
  #pragma unroll
  for (int j = 0; j < 8; ++j) b8[j] = bias[c0 + j];
  #pragma unroll
  for (int r = 0; r < 4; ++r) {
    int gr = r0 + ty * 4 + r;
    if (gr < n) {
      uint4 pk;
      pk.x = packbf(acc[r][0] + b8[0], acc[r][1] + b8[1]);
      pk.y = packbf(acc[r][2] + b8[2], acc[r][3] + b8[3]);
      pk.z = packbf(acc[r][4] + b8[4], acc[r][5] + b8[5]);
      pk.w = packbf(acc[r][6] + b8[6], acc[r][7] + b8[7]);
      *(uint4*)&outp[(size_t)gr * 64 + (size_t)(tx & 15) * 4] = pk;
    }
  }
}

// ---------- CSR build ----------
__global__ void k_hist(const int* __restrict__ dst, int* __restrict__ deg, int E) {
  int e = blockIdx.x * 256 + threadIdx.x;
  if (e < E) atomicAdd(&deg[dst[e]], 1);
}

__global__ void k_scan(const int* __restrict__ deg, int* __restrict__ rowptr, int n) {
  __shared__ int wsum[16];
  __shared__ int s_carry;
  const int t = threadIdx.x;
  const int lane = t & 63, w = t >> 6;
  if (t == 0) s_carry = 0;
  __syncthreads();
  for (int base = 0; base < n; base += 1024) {
    const int i = base + t;
    const int v = (i < n) ? deg[i] : 0;
    int incl = v;
    #pragma unroll
    for (int off = 1; off < 64; off <<= 1) {
      int u = __shfl_up(incl, off);
      if (lane >= off) incl += u;
    }
    if (lane == 63) wsum[w] = incl;
    __syncthreads();
    if (w == 0 && lane < 16) {
      int sv = wsum[lane];
      int si = sv;
      #pragma unroll
      for (int off = 1; off < 16; off <<= 1) {
        int u = __shfl_up(si, off);
        if (lane >= off) si += u;
      }
      wsum[lane] = si - sv;              // exclusive wave offsets
    }
    __syncthreads();
    const int carry = s_carry;
    const int excl = carry + wsum[w] + incl - v;
    if (i < n) rowptr[i] = excl;
    __syncthreads();
    if (t == 1023) s_carry = excl + v;   // running total
    __syncthreads();
  }
  if (t == 0) rowptr[n] = s_carry;
}

__global__ void k_scatter(const int* __restrict__ src, const int* __restrict__ dst,
                          const int* __restrict__ rowptr, int* __restrict__ cursor,
                          int* __restrict__ csr, int E) {
  int e = blockIdx.x * 256 + threadIdx.x;
  if (e < E) {
    int d = dst[e];
    int pos = atomicAdd(&cursor[d], 1);
    csr[rowptr[d] + pos] = src[e];
  }
}

// ---------- per-dst online-softmax attention aggregate ----------
// one wave per dst node; lane l owns channels (2l, 2l+1); head = l>>4
__global__ __launch_bounds__(256) void k_attn(
    const float* __restrict__ x, const unsigned* __restrict__ xlp,
    const unsigned* __restrict__ xrp, const float* __restrict__ att,
    const float* __restrict__ gbias, const int* __restrict__ rowptr,
    const int* __restrict__ csr, float* __restrict__ x2, int n)
{
  const int d = (int)((blockIdx.x * blockDim.x + threadIdx.x) >> 6);
  if (d >= n) return;
  const int l = threadIdx.x & 63;
  const unsigned xr = xrp[(size_t)d * 64 + l];
  const float xr0 = unpk_lo(xr), xr1 = unpk_hi(xr);
  const float2 at = ((const float2*)att)[l];
  const int beg = rowptr[d], end = rowptr[d + 1];
  float m = -1e30f, s = 0.f, acc0 = 0.f, acc1 = 0.f;
  for (int j = beg - 1; j < end; ++j) {       // j==beg-1 -> self loop
    const int sn = (j < beg) ? d : csr[j];
    const unsigned xs = xlp[(size_t)sn * 64 + l];
    const float a0 = unpk_lo(xs), a1 = unpk_hi(xs);
    float e0 = a0 + xr0; e0 = (e0 > 0.f) ? e0 : 0.2f * e0;
    float e1 = a1 + xr1; e1 = (e1 > 0.f) ? e1 : 0.2f * e1;
    float tt = e0 * at.x + e1 * at.y;
    tt += __shfl_xor(tt, 1); tt += __shfl_xor(tt, 2);
    tt += __shfl_xor(tt, 4); tt += __shfl_xor(tt, 8);   // per-head score
    const float nm = fmaxf(m, tt);
    const float sc = __expf(m - nm);
    const float p  = __expf(tt - nm);
    s    = s * sc + p;
    acc0 = acc0 * sc + p * a0;
    acc1 = acc1 * sc + p * a1;
    m = nm;
  }
  const float inv = 1.0f / s;
  const float2 xv = ((const float2*)x)[(size_t)d * 64 + l];
  const float2 gb = ((const float2*)gbias)[l];
  float2 o;
  o.x = xv.x + acc0 * inv + gb.x;
  o.y = xv.y + acc1 * inv + gb.y;
  ((float2*)x2)[(size_t)d * 64 + l] = o;
}

// ---------- fused LN2 + MLP (fc -> gelu -> proj) + residual ----------
__global__ __launch_bounds__(256) void k_mlp(
    const float* __restrict__ x2, const float* __restrict__ ln2w,
    const float* __restrict__ Wfc, const float* __restrict__ Wpj,
    float* __restrict__ out, int n)
{
  __shared__ unsigned u1[32 * 512];            // 64 KB; first 32 KB aliased as h2
  float* h2 = (float*)u1;
  const int t = threadIdx.x;
  const int r0 = blockIdx.x * 64;

  { // LN stage: 4 threads per row, 32 cols each
    const int row = t >> 2, seg = t & 3;
    const int gr = r0 + row;
    const float4* xr4 = (const float4*)(x2 + ((size_t)(gr < n ? gr : 0) * 128 + seg * 32));
    float4 v[8];
    #pragma unroll
    for (int j = 0; j < 8; ++j)
      v[j] = (gr < n) ? xr4[j] : make_float4(0.f, 0.f, 0.f, 0.f);
    float s = 0.f;
    #pragma unroll
    for (int j = 0; j < 8; ++j) s += v[j].x + v[j].y + v[j].z + v[j].w;
    s += __shfl_xor(s, 1); s += __shfl_xor(s, 2);
    const float mean = s * (1.0f / 128.0f);
    float vv = 0.f;
    #pragma unroll
    for (int j = 0; j < 8; ++j) {
      float a = v[j].x - mean, b = v[j].y - mean, c = v[j].z - mean, d = v[j].w - mean;
      vv += a * a + b * b + c * c + d * d;
    }
    vv += __shfl_xor(vv, 1); vv += __shfl_xor(vv, 2);
    const float rstd = rsqrtf(vv * (1.0f / 128.0f) + 1e-5f);
    #pragma unroll
    for (int j = 0; j < 8; ++j) {
      float4 w4 = ((const float4*)ln2w)[seg * 8 + j];
      float4 o;
      o.x = (v[j].x - mean) * rstd * w4.x;
      o.y = (v[j].y - mean) * rstd * w4.y;
      o.z = (v[j].z - mean) * rstd * w4.z;
      o.w = (v[j].w - mean) * rstd * w4.w;
      ((float4*)h2)[row * 32 + seg * 8 + j] = o;
    }
  }
  __syncthreads();

  const int tx = t & 31, ty = t >> 5;
  // GEMM1: out1[64][512] = h2 @ Wfc ; thread: 8 rows x 16 cols
  float acc[8][16];
  #pragma unroll
  for (int r = 0; r < 8; ++r) {
    #pragma unroll
    for (int j = 0; j < 16; ++j) acc[r][j] = 0.f;
  }
  for (int k = 0; k < 128; k += 4) {
    float4 a4[8];
    #pragma unroll
    for (int r = 0; r < 8; ++r)
      a4[r] = *(const float4*)&h2[(ty * 8 + r) * 128 + k];
    #pragma unroll
    for (int kk = 0; kk < 4; ++kk) {
      const float* wr = Wfc + (size_t)(k + kk) * 512 + tx * 16;
      const float4 b0 = *(const float4*)(wr + 0);
      const float4 b1 = *(const float4*)(wr + 4);
      const float4 b2 = *(const float4*)(wr + 8);
      const float4 b3 = *(const float4*)(wr + 12);
      #pragma unroll
      for (int r = 0; r < 8; ++r) {
        const float a = fcomp(a4[r], kk);
        acc[r][0]  += a * b0.x; acc[r][1]  += a * b0.y;
        acc[r][2]  += a * b0.z; acc[r][3]  += a * b0.w;
        acc[r][4]  += a * b1.x; acc[r][5]  += a * b1.y;
        acc[r][6]  += a * b1.z; acc[r][7]  += a * b1.w;
        acc[r][8]  += a * b2.x; acc[r][9]  += a * b2.y;
        acc[r][10] += a * b2.z; acc[r][11] += a * b2.w;
        acc[r][12] += a * b3.x; acc[r][13] += a * b3.y;
        acc[r][14] += a * b3.z; acc[r][15] += a * b3.w;
      }
    }
  }
  __syncthreads();   // all h2 reads done; safe to overwrite with u1
  // gelu + pack row-pairs (rows 2p,2p+1 -> one u32) into LDS
  #pragma unroll
  for (int q = 0; q < 4; ++q) {
    #pragma unroll
    for (int j4 = 0; j4 < 4; ++j4) {
      uint4 pk;
      pk.x = packbf(gelu_f(acc[2*q][j4*4+0]), gelu_f(acc[2*q+1][j4*4+0]));
      pk.y = packbf(gelu_f(acc[2*q][j4*4+1]), gelu_f(acc[2*q+1][j4*4+1]));
      pk.z = packbf(gelu_f(acc[2*q][j4*4+2]), gelu_f(acc[2*q+1][j4*4+2]));
      pk.w = packbf(gelu_f(acc[2*q][j4*4+3]), gelu_f(acc[2*q+1][j4*4+3]));
      *(uint4*)&u1[(size_t)(ty * 4 + q) * 512 + tx * 16 + j4 * 4] = pk;
    }
  }
  __syncthreads();

  // GEMM2: out2[64][128] = gelu1 @ Wpj ; thread: 8 rows x 4 cols
  float acc2[8][4];
  #pragma unroll
  for (int r = 0; r < 8; ++r) {
    #pragma unroll
    for (int j = 0; j < 4; ++j) acc2[r][j] = 0.f;
  }
  for (int k = 0; k < 512; k += 4) {
    uint4 ap[4];
    #pragma unroll
    for (int q = 0; q < 4; ++q)
      ap[q] = *(const uint4*)&u1[(size_t)(ty * 4 + q) * 512 + k];
    #pragma unroll
    for (int kk = 0; kk < 4; ++kk) {
      const float4 b = *(const float4*)&Wpj[(size_t)(k + kk) * 128 + tx * 4];
      #pragma unroll
      for (int q = 0; q < 4; ++q) {
        const unsigned u = ucomp(ap[q], kk);
        const float lo = unpk_lo(u), hi = unpk_hi(u);
        acc2[2*q][0]   += lo * b.x; acc2[2*q][1]   += lo * b.y;
        acc2[2*q][2]   += lo * b.z; acc2[2*q][3]   += lo * b.w;
        acc2[2*q+1][0] += hi * b.x; acc2[2*q+1][1] += hi * b.y;
        acc2[2*q+1][2] += hi * b.z; acc2[2*q+1][3] += hi * b.w;
      }
    }
  }
  #pragma unroll
  for (int r = 0; r < 8; ++r) {
    const int gr = r0 + ty * 8 + r;
    if (gr < n) {
      const float4 xv = *(const float4*)&x2[(size_t)gr * 128 + tx * 4];
      float4 o;
      o.x = xv.x + acc2[r][0];
      o.y = xv.y + acc2[r][1];
      o.z = xv.z + acc2[r][2];
      o.w = xv.w + acc2[r][3];
      *(float4*)&out[(size_t)gr * 128 + tx * 4] = o;
    }
  }
}

// ---------- launch ----------
extern "C" void kernel_launch(void* const* d_in, const int* in_sizes, int n_in,
                              void* d_out, int out_size, void* d_ws, size_t ws_size,
                              hipStream_t stream)
{
  (void)n_in; (void)out_size; (void)ws_size;
  const float* x     = (const float*)d_in[0];
  const int*   ei    = (const int*)d_in[1];
  const float* ln1w  = (const float*)d_in[2];
  const float* Wl    = (const float*)d_in[3];
  const float* bl    = (const float*)d_in[4];
  const float* Wr    = (const float*)d_in[5];
  const float* br    = (const float*)d_in[6];
  const float* att   = (const float*)d_in[7];
  const float* gbias = (const float*)d_in[8];
  const float* ln2w  = (const float*)d_in[9];
  const float* Wfc   = (const float*)d_in[10];
  const float* Wpj   = (const float*)d_in[11];
  float* out = (float*)d_out;

  const int n = in_sizes[0] / 128;
  const int E = in_sizes[1] / 2;

  char* w = (char*)d_ws;
  unsigned* xlp = (unsigned*)w; w += (size_t)n * 64 * 4;
  unsigned* xrp = (unsigned*)w; w += (size_t)n * 64 * 4;
  float*    x2  = (float*)w;    w += (size_t)n * 128 * 4;
  int*      deg = (int*)w;      w += (size_t)n * 4;
  int*   rowptr = (int*)w;      w += (size_t)(n + 1) * 4;
  int*   cursor = (int*)w;      w += (size_t)n * 4;
  int*      csr = (int*)w;      w += (size_t)E * 4;

  hipMemsetAsync(deg, 0, (size_t)n * 4, stream);
  hipMemsetAsync(cursor, 0, (size_t)n * 4, stream);

  k_gemlr<<<(n + 31) / 32, 256, 0, stream>>>(x, ln1w, Wl, bl, Wr, br, xlp, xrp, n);
  k_hist<<<(E + 255) / 256, 256, 0, stream>>>(ei + E, deg, E);
  k_scan<<<1, 1024, 0, stream>>>(deg, rowptr, n);
  k_scatter<<<(E + 255) / 256, 256, 0, stream>>>(ei, ei + E, rowptr, cursor, csr, E);
  k_attn<<<(n + 3) / 4, 256, 0, stream>>>(x, xlp, xrp, att, gbias, rowptr, csr, x2, n);
  k_mlp<<<(n + 63) / 64, 256, 0, stream>>>(x2, ln2w, Wfc, Wpj, out, n);
}

// Round 2
// 444.020 us; speedup vs baseline: 1.4561x; 1.4561x over previous
//
#include <hip/hip_runtime.h>
#include <math.h>

typedef __attribute__((ext_vector_type(8))) short bf16x8;
typedef __attribute__((ext_vector_type(4))) float f32x4;

// ---------- helpers ----------
__device__ __forceinline__ unsigned bf16b(float f) {
  unsigned u = __float_as_uint(f);
  return (u + 0x7fffu + ((u >> 16) & 1u)) >> 16;   // RNE
}
__device__ __forceinline__ unsigned packbf(float lo, float hi) {
  return bf16b(lo) | (bf16b(hi) << 16);
}
__device__ __forceinline__ float unpk_lo(unsigned u) { return __uint_as_float(u << 16); }
__device__ __forceinline__ float unpk_hi(unsigned u) { return __uint_as_float(u & 0xffff0000u); }
__device__ __forceinline__ float gelu_f(float v) {
  return 0.5f * v * (1.0f + erff(v * 0.70710678118654752f));
}

// ---------- weight transpose + bf16 convert: dst[c*K + k] = bf16(src[k*C + c]) ----------
__global__ void k_cvt(const float* __restrict__ src, unsigned short* __restrict__ dst,
                      int lgK, int C, int total) {
  int i = blockIdx.x * 256 + threadIdx.x;
  if (i < total) {
    int k = i & ((1 << lgK) - 1);
    int c = i >> lgK;
    dst[i] = (unsigned short)bf16b(src[(size_t)k * C + c]);
  }
}

// ---------- fused LN1 + [Wl|Wr] MFMA GEMM -> bf16 xl/xr ----------
// xl16/xr16: u16[n][128]; u32 view at [i*64+l] = channels (2l,2l+1) — matches k_attn.
__global__ __launch_bounds__(256, 2) void k_gemlr(
    const float* __restrict__ x, const float* __restrict__ ln1w,
    const unsigned short* __restrict__ Wl_t, const float* __restrict__ bl,
    const unsigned short* __restrict__ Wr_t, const float* __restrict__ br,
    unsigned short* __restrict__ xl16, unsigned short* __restrict__ xr16, int n)
{
  __shared__ __align__(16) unsigned short hs[64 * 128];   // 16 KB, swizzled bf16
  const int t = threadIdx.x;
  const int lane = t & 63, w = t >> 6;
  const int r0 = blockIdx.x * 64;

  { // LN1: 4 threads per row, 32 cols each
    const int row = t >> 2, seg = t & 3;
    const int gr = r0 + row;
    const float4* xr4 = (const float4*)(x + (size_t)(gr < n ? gr : 0) * 128) + seg * 8;
    float4 v[8];
    #pragma unroll
    for (int j = 0; j < 8; ++j) v[j] = (gr < n) ? xr4[j] : make_float4(0.f,0.f,0.f,0.f);
    float s = 0.f;
    #pragma unroll
    for (int j = 0; j < 8; ++j) s += v[j].x + v[j].y + v[j].z + v[j].w;
    s += __shfl_xor(s, 1); s += __shfl_xor(s, 2);
    const float mean = s * (1.0f / 128.0f);
    float vv = 0.f;
    #pragma unroll
    for (int j = 0; j < 8; ++j) {
      float a = v[j].x - mean, b = v[j].y - mean, c = v[j].z - mean, d = v[j].w - mean;
      vv += a * a + b * b + c * c + d * d;
    }
    vv += __shfl_xor(vv, 1); vv += __shfl_xor(vv, 2);
    const float rstd = rsqrtf(vv * (1.0f / 128.0f) + 1e-5f);
    #pragma unroll
    for (int j2 = 0; j2 < 4; ++j2) {
      float4 wa = ((const float4*)ln1w)[seg * 8 + 2 * j2];
      float4 wb = ((const float4*)ln1w)[seg * 8 + 2 * j2 + 1];
      const float4 va = v[2 * j2], vb = v[2 * j2 + 1];
      uint4 pk;
      pk.x = packbf((va.x - mean) * rstd * wa.x, (va.y - mean) * rstd * wa.y);
      pk.y = packbf((va.z - mean) * rstd * wa.z, (va.w - mean) * rstd * wa.w);
      pk.z = packbf((vb.x - mean) * rstd * wb.x, (vb.y - mean) * rstd * wb.y);
      pk.w = packbf((vb.z - mean) * rstd * wb.z, (vb.w - mean) * rstd * wb.w);
      int byteoff = (row * 256 + (seg * 4 + j2) * 16) ^ ((row & 7) << 4);
      *(uint4*)((char*)hs + byteoff) = pk;
    }
  }
  __syncthreads();

  const int l15 = lane & 15, lg = lane >> 4;
  const unsigned short* __restrict__ Wt = (w < 2) ? Wl_t : Wr_t;
  const float* __restrict__ bias = (w < 2) ? bl : br;
  unsigned short* __restrict__ outp = (w < 2) ? xl16 : xr16;
  const int cbase = (w & 1) * 64;

  f32x4 acc[4][4];
  #pragma unroll
  for (int m = 0; m < 4; ++m)
    #pragma unroll
    for (int nf = 0; nf < 4; ++nf) acc[m][nf] = (f32x4){0.f, 0.f, 0.f, 0.f};

  #pragma unroll
  for (int ks = 0; ks < 4; ++ks) {
    bf16x8 b[4];
    #pragma unroll
    for (int nf = 0; nf < 4; ++nf) {
      const int c = cbase + nf * 16 + l15;
      b[nf] = *(const bf16x8*)(Wt + (size_t)c * 128 + ks * 32 + lg * 8);
    }
    bf16x8 a[4];
    #pragma unroll
    for (int m = 0; m < 4; ++m) {
      const int row = m * 16 + l15;
      const int byteoff = (row * 256 + ks * 64 + lg * 16) ^ ((row & 7) << 4);
      a[m] = *(const bf16x8*)((const char*)hs + byteoff);
    }
    #pragma unroll
    for (int m = 0; m < 4; ++m)
      #pragma unroll
      for (int nf = 0; nf < 4; ++nf)
        acc[m][nf] = __builtin_amdgcn_mfma_f32_16x16x32_bf16(a[m], b[nf], acc[m][nf], 0, 0, 0);
  }

  #pragma unroll
  for (int nf = 0; nf < 4; ++nf) {
    const int c = cbase + nf * 16 + l15;
    const float bv = bias[c];
    #pragma unroll
    for (int m = 0; m < 4; ++m) {
      #pragma unroll
      for (int r = 0; r < 4; ++r) {
        const int gr = r0 + m * 16 + lg * 4 + r;
        if (gr < n)
          outp[(size_t)gr * 128 + c] = (unsigned short)bf16b(acc[m][nf][r] + bv);
      }
    }
  }
}

// ---------- CSR build ----------
__global__ void k_hist(const int* __restrict__ dst, int* __restrict__ deg, int E) {
  int e = blockIdx.x * 256 + threadIdx.x;
  if (e < E) atomicAdd(&deg[dst[e]], 1);
}

__global__ void k_scan(const int* __restrict__ deg, int* __restrict__ rowptr, int n) {
  __shared__ int wsum[16];
  __shared__ int s_carry;
  const int t = threadIdx.x;
  const int lane = t & 63, w = t >> 6;
  if (t == 0) s_carry = 0;
  __syncthreads();
  for (int base = 0; base < n; base += 1024) {
    const int i = base + t;
    const int v = (i < n) ? deg[i] : 0;
    int incl = v;
    #pragma unroll
    for (int off = 1; off < 64; off <<= 1) {
      int u = __shfl_up(incl, off);
      if (lane >= off) incl += u;
    }
    if (lane == 63) wsum[w] = incl;
    __syncthreads();
    if (w == 0 && lane < 16) {
      int sv = wsum[lane];
      int si = sv;
      #pragma unroll
      for (int off = 1; off < 16; off <<= 1) {
        int u = __shfl_up(si, off);
        if (lane >= off) si += u;
      }
      wsum[lane] = si - sv;              // exclusive wave offsets
    }
    __syncthreads();
    const int carry = s_carry;
    const int excl = carry + wsum[w] + incl - v;
    if (i < n) rowptr[i] = excl;
    __syncthreads();
    if (t == 1023) s_carry = excl + v;   // running total
    __syncthreads();
  }
  if (t == 0) rowptr[n] = s_carry;
}

__global__ void k_scatter(const int* __restrict__ src, const int* __restrict__ dst,
                          const int* __restrict__ rowptr, int* __restrict__ cursor,
                          int* __restrict__ csr, int E) {
  int e = blockIdx.x * 256 + threadIdx.x;
  if (e < E) {
    int d = dst[e];
    int pos = atomicAdd(&cursor[d], 1);
    csr[rowptr[d] + pos] = src[e];
  }
}

// ---------- per-dst online-softmax attention aggregate ----------
// one wave per dst node; lane l owns channels (2l, 2l+1); head = l>>4
__global__ __launch_bounds__(256) void k_attn(
    const float* __restrict__ x, const unsigned* __restrict__ xlp,
    const unsigned* __restrict__ xrp, const float* __restrict__ att,
    const float* __restrict__ gbias, const int* __restrict__ rowptr,
    const int* __restrict__ csr, float* __restrict__ x2, int n)
{
  const int d = (int)((blockIdx.x * blockDim.x + threadIdx.x) >> 6);
  if (d >= n) return;
  const int l = threadIdx.x & 63;
  const unsigned xr = xrp[(size_t)d * 64 + l];
  const float xr0 = unpk_lo(xr), xr1 = unpk_hi(xr);
  const float2 at = ((const float2*)att)[l];
  const int beg = rowptr[d], end = rowptr[d + 1];
  float m = -1e30f, s = 0.f, acc0 = 0.f, acc1 = 0.f;
  for (int j = beg - 1; j < end; ++j) {       // j==beg-1 -> self loop
    const int sn = (j < beg) ? d : csr[j];
    const unsigned xs = xlp[(size_t)sn * 64 + l];
    const float a0 = unpk_lo(xs), a1 = unpk_hi(xs);
    float e0 = a0 + xr0; e0 = (e0 > 0.f) ? e0 : 0.2f * e0;
    float e1 = a1 + xr1; e1 = (e1 > 0.f) ? e1 : 0.2f * e1;
    float tt = e0 * at.x + e1 * at.y;
    tt += __shfl_xor(tt, 1); tt += __shfl_xor(tt, 2);
    tt += __shfl_xor(tt, 4); tt += __shfl_xor(tt, 8);   // per-head score
    const float nm = fmaxf(m, tt);
    const float sc = __expf(m - nm);
    const float p  = __expf(tt - nm);
    s    = s * sc + p;
    acc0 = acc0 * sc + p * a0;
    acc1 = acc1 * sc + p * a1;
    m = nm;
  }
  const float inv = 1.0f / s;
  const float2 xv = ((const float2*)x)[(size_t)d * 64 + l];
  const float2 gb = ((const float2*)gbias)[l];
  float2 o;
  o.x = xv.x + acc0 * inv + gb.x;
  o.y = xv.y + acc1 * inv + gb.y;
  ((float2*)x2)[(size_t)d * 64 + l] = o;
}

// ---------- fused LN2 + MFMA MLP (fc -> gelu -> proj) + residual ----------
__global__ __launch_bounds__(256, 2) void k_mlp(
    const float* __restrict__ x2, const float* __restrict__ ln2w,
    const unsigned short* __restrict__ Wfc_t, const unsigned short* __restrict__ Wpj_t,
    float* __restrict__ out, int n)
{
  __shared__ __align__(16) unsigned short sm[32768];   // 64 KB; h2 in first 16 KB, then g[64][512]
  const int t = threadIdx.x;
  const int lane = t & 63, w = t >> 6;
  const int r0 = blockIdx.x * 64;

  { // LN2: 4 threads per row, 32 cols each -> swizzled bf16 h2[64][128]
    const int row = t >> 2, seg = t & 3;
    const int gr = r0 + row;
    const float4* xr4 = (const float4*)(x2 + (size_t)(gr < n ? gr : 0) * 128) + seg * 8;
    float4 v[8];
    #pragma unroll
    for (int j = 0; j < 8; ++j) v[j] = (gr < n) ? xr4[j] : make_float4(0.f,0.f,0.f,0.f);
    float s = 0.f;
    #pragma unroll
    for (int j = 0; j < 8; ++j) s += v[j].x + v[j].y + v[j].z + v[j].w;
    s += __shfl_xor(s, 1); s += __shfl_xor(s, 2);
    const float mean = s * (1.0f / 128.0f);
    float vv = 0.f;
    #pragma unroll
    for (int j = 0; j < 8; ++j) {
      float a = v[j].x - mean, b = v[j].y - mean, c = v[j].z - mean, d = v[j].w - mean;
      vv += a * a + b * b + c * c + d * d;
    }
    vv += __shfl_xor(vv, 1); vv += __shfl_xor(vv, 2);
    const float rstd = rsqrtf(vv * (1.0f / 128.0f) + 1e-5f);
    #pragma unroll
    for (int j2 = 0; j2 < 4; ++j2) {
      float4 wa = ((const float4*)ln2w)[seg * 8 + 2 * j2];
      float4 wb = ((const float4*)ln2w)[seg * 8 + 2 * j2 + 1];
      const float4 va = v[2 * j2], vb = v[2 * j2 + 1];
      uint4 pk;
      pk.x = packbf((va.x - mean) * rstd * wa.x, (va.y - mean) * rstd * wa.y);
      pk.y = packbf((va.z - mean) * rstd * wa.z, (va.w - mean) * rstd * wa.w);
      pk.z = packbf((vb.x - mean) * rstd * wb.x, (vb.y - mean) * rstd * wb.y);
      pk.w = packbf((vb.z - mean) * rstd * wb.z, (vb.w - mean) * rstd * wb.w);
      int byteoff = (row * 256 + (seg * 4 + j2) * 16) ^ ((row & 7) << 4);
      *(uint4*)((char*)sm + byteoff) = pk;
    }
  }
  __syncthreads();

  const int l15 = lane & 15, lg = lane >> 4;

  // GEMM1: out1[64][512] = h2 @ Wfc ; wave w -> cols w*128..+127
  f32x4 acc[4][8];
  #pragma unroll
  for (int m = 0; m < 4; ++m)
    #pragma unroll
    for (int nf = 0; nf < 8; ++nf) acc[m][nf] = (f32x4){0.f, 0.f, 0.f, 0.f};

  #pragma unroll
  for (int ks = 0; ks < 4; ++ks) {
    bf16x8 b[8];
    #pragma unroll
    for (int nf = 0; nf < 8; ++nf) {
      const int c = w * 128 + nf * 16 + l15;
      b[nf] = *(const bf16x8*)(Wfc_t + (size_t)c * 128 + ks * 32 + lg * 8);
    }
    bf16x8 a[4];
    #pragma unroll
    for (int m = 0; m < 4; ++m) {
      const int row = m * 16 + l15;
      const int byteoff = (row * 256 + ks * 64 + lg * 16) ^ ((row & 7) << 4);
      a[m] = *(const bf16x8*)((const char*)sm + byteoff);
    }
    #pragma unroll
    for (int m = 0; m < 4; ++m)
      #pragma unroll
      for (int nf = 0; nf < 8; ++nf)
        acc[m][nf] = __builtin_amdgcn_mfma_f32_16x16x32_bf16(a[m], b[nf], acc[m][nf], 0, 0, 0);
  }
  __syncthreads();   // h2 reads done; reuse sm as g[64][512] bf16 (swizzled)

  #pragma unroll
  for (int m = 0; m < 4; ++m)
    #pragma unroll
    for (int nf = 0; nf < 8; ++nf)
      #pragma unroll
      for (int r = 0; r < 4; ++r) {
        const int row = m * 16 + lg * 4 + r;
        const int col = w * 128 + nf * 16 + l15;
        const int byteoff = (row * 1024 + col * 2) ^ ((row & 7) << 4);
        *(unsigned short*)((char*)sm + byteoff) = (unsigned short)bf16b(gelu_f(acc[m][nf][r]));
      }
  __syncthreads();

  // GEMM2: out2[64][128] = g @ Wpj ; wave w -> cols w*32..+31
  f32x4 acc2[4][2];
  #pragma unroll
  for (int m = 0; m < 4; ++m) {
    acc2[m][0] = (f32x4){0.f, 0.f, 0.f, 0.f};
    acc2[m][1] = (f32x4){0.f, 0.f, 0.f, 0.f};
  }
  #pragma unroll 4
  for (int ks = 0; ks < 16; ++ks) {
    bf16x8 b2[2];
    #pragma unroll
    for (int nf = 0; nf < 2; ++nf) {
      const int c = w * 32 + nf * 16 + l15;
      b2[nf] = *(const bf16x8*)(Wpj_t + (size_t)c * 512 + ks * 32 + lg * 8);
    }
    bf16x8 a2[4];
    #pragma unroll
    for (int m = 0; m < 4; ++m) {
      const int row = m * 16 + l15;
      const int byteoff = (row * 1024 + ks * 64 + lg * 16) ^ ((row & 7) << 4);
      a2[m] = *(const bf16x8*)((const char*)sm + byteoff);
    }
    #pragma unroll
    for (int m = 0; m < 4; ++m) {
      acc2[m][0] = __builtin_amdgcn_mfma_f32_16x16x32_bf16(a2[m], b2[0], acc2[m][0], 0, 0, 0);
      acc2[m][1] = __builtin_amdgcn_mfma_f32_16x16x32_bf16(a2[m], b2[1], acc2[m][1], 0, 0, 0);
    }
  }

  // residual epilogue
  #pragma unroll
  for (int m = 0; m < 4; ++m)
    #pragma unroll
    for (int nf = 0; nf < 2; ++nf) {
      const int col = w * 32 + nf * 16 + l15;
      #pragma unroll
      for (int r = 0; r < 4; ++r) {
        const int gr = r0 + m * 16 + lg * 4 + r;
        if (gr < n)
          out[(size_t)gr * 128 + col] = x2[(size_t)gr * 128 + col] + acc2[m][nf][r];
      }
    }
}

// ---------- launch ----------
extern "C" void kernel_launch(void* const* d_in, const int* in_sizes, int n_in,
                              void* d_out, int out_size, void* d_ws, size_t ws_size,
                              hipStream_t stream)
{
  (void)n_in; (void)out_size; (void)ws_size;
  const float* x     = (const float*)d_in[0];
  const int*   ei    = (const int*)d_in[1];
  const float* ln1w  = (const float*)d_in[2];
  const float* Wl    = (const float*)d_in[3];
  const float* bl    = (const float*)d_in[4];
  const float* Wr    = (const float*)d_in[5];
  const float* br    = (const float*)d_in[6];
  const float* att   = (const float*)d_in[7];
  const float* gbias = (const float*)d_in[8];
  const float* ln2w  = (const float*)d_in[9];
  const float* Wfc   = (const float*)d_in[10];
  const float* Wpj   = (const float*)d_in[11];
  float* out = (float*)d_out;

  const int n = in_sizes[0] / 128;
  const int E = in_sizes[1] / 2;

  char* w = (char*)d_ws;
  unsigned short* xl16 = (unsigned short*)w; w += (size_t)n * 128 * 2;
  unsigned short* xr16 = (unsigned short*)w; w += (size_t)n * 128 * 2;
  float*    x2  = (float*)w;    w += (size_t)n * 128 * 4;
  int*      deg = (int*)w;      w += (size_t)n * 4;
  int*   rowptr = (int*)w;      w += (size_t)(n + 1) * 4;
  int*   cursor = (int*)w;      w += (size_t)n * 4;
  int*      csr = (int*)w;      w += (size_t)E * 4;
  unsigned short* Wl_t  = (unsigned short*)w; w += 128 * 128 * 2;
  unsigned short* Wr_t  = (unsigned short*)w; w += 128 * 128 * 2;
  unsigned short* Wfc_t = (unsigned short*)w; w += 512 * 128 * 2;
  unsigned short* Wpj_t = (unsigned short*)w; w += 128 * 512 * 2;

  hipMemsetAsync(deg, 0, (size_t)n * 4, stream);
  hipMemsetAsync(cursor, 0, (size_t)n * 4, stream);

  k_cvt<<<(128 * 128 + 255) / 256, 256, 0, stream>>>(Wl,  Wl_t,  7, 128, 128 * 128);
  k_cvt<<<(128 * 128 + 255) / 256, 256, 0, stream>>>(Wr,  Wr_t,  7, 128, 128 * 128);
  k_cvt<<<(512 * 128 + 255) / 256, 256, 0, stream>>>(Wfc, Wfc_t, 7, 512, 512 * 128);
  k_cvt<<<(512 * 128 + 255) / 256, 256, 0, stream>>>(Wpj, Wpj_t, 9, 128, 512 * 128);

  k_gemlr<<<(n + 63) / 64, 256, 0, stream>>>(x, ln1w, Wl_t, bl, Wr_t, br, xl16, xr16, n);
  k_hist<<<(E + 255) / 256, 256, 0, stream>>>(ei + E, deg, E);
  k_scan<<<1, 1024, 0, stream>>>(deg, rowptr, n);
  k_scatter<<<(E + 255) / 256, 256, 0, stream>>>(ei, ei + E, rowptr, cursor, csr, E);
  k_attn<<<(n + 3) / 4, 256, 0, stream>>>(x, (const unsigned*)xl16, (const unsigned*)xr16,
                                          att, gbias, rowptr, csr, x2, n);
  k_mlp<<<(n + 63) / 64, 256, 0, stream>>>(x2, ln2w, Wfc_t, Wpj_t, out, n);
}

// Round 3
// 386.648 us; speedup vs baseline: 1.6721x; 1.1484x over previous
//
#include <hip/hip_runtime.h>
#include <math.h>

typedef __attribute__((ext_vector_type(8))) short bf16x8;
typedef __attribute__((ext_vector_type(4))) float f32x4;

// ---------- helpers ----------
__device__ __forceinline__ unsigned bf16b(float f) {
  unsigned u = __float_as_uint(f);
  return (u + 0x7fffu + ((u >> 16) & 1u)) >> 16;   // RNE
}
__device__ __forceinline__ unsigned packbf(float lo, float hi) {
  return bf16b(lo) | (bf16b(hi) << 16);
}
__device__ __forceinline__ float unpk_lo(unsigned u) { return __uint_as_float(u << 16); }
__device__ __forceinline__ float unpk_hi(unsigned u) { return __uint_as_float(u & 0xffff0000u); }
__device__ __forceinline__ float gelu_f(float v) {
  return 0.5f * v * (1.0f + erff(v * 0.70710678118654752f));
}

// ---------- weight transpose + bf16 convert: dst[c*K + k] = bf16(src[k*C + c]) ----------
__global__ void k_cvt(const float* __restrict__ src, unsigned short* __restrict__ dst,
                      int lgK, int C, int total) {
  int i = blockIdx.x * 256 + threadIdx.x;
  if (i < total) {
    int k = i & ((1 << lgK) - 1);
    int c = i >> lgK;
    dst[i] = (unsigned short)bf16b(src[(size_t)k * C + c]);
  }
}

// ---------- fused LN1 + [Wl|Wr] MFMA GEMM -> bf16 xl/xr ----------
__global__ __launch_bounds__(256, 2) void k_gemlr(
    const float* __restrict__ x, const float* __restrict__ ln1w,
    const unsigned short* __restrict__ Wl_t, const float* __restrict__ bl,
    const unsigned short* __restrict__ Wr_t, const float* __restrict__ br,
    unsigned short* __restrict__ xl16, unsigned short* __restrict__ xr16, int n)
{
  __shared__ __align__(16) unsigned short hs[64 * 128];   // 16 KB, swizzled bf16
  const int t = threadIdx.x;
  const int lane = t & 63, w = t >> 6;
  const int r0 = blockIdx.x * 64;

  { // LN1: 4 threads per row, 32 cols each
    const int row = t >> 2, seg = t & 3;
    const int gr = r0 + row;
    const float4* xr4 = (const float4*)(x + (size_t)(gr < n ? gr : 0) * 128) + seg * 8;
    float4 v[8];
    #pragma unroll
    for (int j = 0; j < 8; ++j) v[j] = (gr < n) ? xr4[j] : make_float4(0.f,0.f,0.f,0.f);
    float s = 0.f;
    #pragma unroll
    for (int j = 0; j < 8; ++j) s += v[j].x + v[j].y + v[j].z + v[j].w;
    s += __shfl_xor(s, 1); s += __shfl_xor(s, 2);
    const float mean = s * (1.0f / 128.0f);
    float vv = 0.f;
    #pragma unroll
    for (int j = 0; j < 8; ++j) {
      float a = v[j].x - mean, b = v[j].y - mean, c = v[j].z - mean, d = v[j].w - mean;
      vv += a * a + b * b + c * c + d * d;
    }
    vv += __shfl_xor(vv, 1); vv += __shfl_xor(vv, 2);
    const float rstd = rsqrtf(vv * (1.0f / 128.0f) + 1e-5f);
    #pragma unroll
    for (int j2 = 0; j2 < 4; ++j2) {
      float4 wa = ((const float4*)ln1w)[seg * 8 + 2 * j2];
      float4 wb = ((const float4*)ln1w)[seg * 8 + 2 * j2 + 1];
      const float4 va = v[2 * j2], vb = v[2 * j2 + 1];
      uint4 pk;
      pk.x = packbf((va.x - mean) * rstd * wa.x, (va.y - mean) * rstd * wa.y);
      pk.y = packbf((va.z - mean) * rstd * wa.z, (va.w - mean) * rstd * wa.w);
      pk.z = packbf((vb.x - mean) * rstd * wb.x, (vb.y - mean) * rstd * wb.y);
      pk.w = packbf((vb.z - mean) * rstd * wb.z, (vb.w - mean) * rstd * wb.w);
      int byteoff = (row * 256 + (seg * 4 + j2) * 16) ^ ((row & 7) << 4);
      *(uint4*)((char*)hs + byteoff) = pk;
    }
  }
  __syncthreads();

  const int l15 = lane & 15, lg = lane >> 4;
  const unsigned short* __restrict__ Wt = (w < 2) ? Wl_t : Wr_t;
  const float* __restrict__ bias = (w < 2) ? bl : br;
  unsigned short* __restrict__ outp = (w < 2) ? xl16 : xr16;
  const int cbase = (w & 1) * 64;

  f32x4 acc[4][4];
  #pragma unroll
  for (int m = 0; m < 4; ++m)
    #pragma unroll
    for (int nf = 0; nf < 4; ++nf) acc[m][nf] = (f32x4){0.f, 0.f, 0.f, 0.f};

  #pragma unroll
  for (int ks = 0; ks < 4; ++ks) {
    bf16x8 b[4];
    #pragma unroll
    for (int nf = 0; nf < 4; ++nf) {
      const int c = cbase + nf * 16 + l15;
      b[nf] = *(const bf16x8*)(Wt + (size_t)c * 128 + ks * 32 + lg * 8);
    }
    bf16x8 a[4];
    #pragma unroll
    for (int m = 0; m < 4; ++m) {
      const int row = m * 16 + l15;
      const int byteoff = (row * 256 + ks * 64 + lg * 16) ^ ((row & 7) << 4);
      a[m] = *(const bf16x8*)((const char*)hs + byteoff);
    }
    #pragma unroll
    for (int m = 0; m < 4; ++m)
      #pragma unroll
      for (int nf = 0; nf < 4; ++nf)
        acc[m][nf] = __builtin_amdgcn_mfma_f32_16x16x32_bf16(a[m], b[nf], acc[m][nf], 0, 0, 0);
  }

  #pragma unroll
  for (int nf = 0; nf < 4; ++nf) {
    const int c = cbase + nf * 16 + l15;
    const float bv = bias[c];
    #pragma unroll
    for (int m = 0; m < 4; ++m) {
      #pragma unroll
      for (int r = 0; r < 4; ++r) {
        const int gr = r0 + m * 16 + lg * 4 + r;
        if (gr < n)
          outp[(size_t)gr * 128 + c] = (unsigned short)bf16b(acc[m][nf][r] + bv);
      }
    }
  }
}

// ---------- CSR build ----------
__global__ void k_hist(const int* __restrict__ dst, int* __restrict__ deg, int E) {
  int e = blockIdx.x * 256 + threadIdx.x;
  if (e < E) atomicAdd(&deg[dst[e]], 1);
}

// per-block sums
__global__ void k_scan1(const int* __restrict__ deg, int* __restrict__ bsum, int n) {
  __shared__ int red[4];
  const int t = threadIdx.x, lane = t & 63, w = t >> 6;
  const int i = blockIdx.x * 256 + t;
  int v = (i < n) ? deg[i] : 0;
  #pragma unroll
  for (int off = 1; off < 64; off <<= 1) v += __shfl_xor(v, off);
  if (lane == 0) red[w] = v;
  __syncthreads();
  if (t == 0) bsum[blockIdx.x] = red[0] + red[1] + red[2] + red[3];
}

// exclusive scan of block sums (nb <= 1024), in place; also rowptr[n] = E
__global__ void k_scan2(int* __restrict__ bsum, int nb, int* __restrict__ rowptr,
                        int n, int Etot) {
  __shared__ int wsum[16];
  const int t = threadIdx.x, lane = t & 63, w = t >> 6;
  const int v = (t < nb) ? bsum[t] : 0;
  int incl = v;
  #pragma unroll
  for (int off = 1; off < 64; off <<= 1) {
    int u = __shfl_up(incl, off);
    if (lane >= off) incl += u;
  }
  if (lane == 63) wsum[w] = incl;
  __syncthreads();
  if (w == 0 && lane < 16) {
    int sv = wsum[lane];
    int si = sv;
    #pragma unroll
    for (int off = 1; off < 16; off <<= 1) {
      int u = __shfl_up(si, off);
      if (lane >= off) si += u;
    }
    wsum[lane] = si - sv;
  }
  __syncthreads();
  if (t < nb) bsum[t] = wsum[w] + incl - v;
  if (t == 0) rowptr[n] = Etot;
}

// per-block exclusive scan + block offset -> rowptr
__global__ void k_scan3(const int* __restrict__ deg, const int* __restrict__ bsum,
                        int* __restrict__ rowptr, int n) {
  __shared__ int ws4[4];
  const int t = threadIdx.x, lane = t & 63, w = t >> 6;
  const int i = blockIdx.x * 256 + t;
  const int v = (i < n) ? deg[i] : 0;
  int incl = v;
  #pragma unroll
  for (int off = 1; off < 64; off <<= 1) {
    int u = __shfl_up(incl, off);
    if (lane >= off) incl += u;
  }
  if (lane == 63) ws4[w] = incl;
  __syncthreads();
  if (t == 0) {
    int s1 = ws4[0], s2 = s1 + ws4[1], s3 = s2 + ws4[2];
    ws4[0] = 0; ws4[1] = s1; ws4[2] = s2; ws4[3] = s3;
  }
  __syncthreads();
  if (i < n) rowptr[i] = bsum[blockIdx.x] + ws4[w] + incl - v;
}

__global__ void k_scatter(const int* __restrict__ src, const int* __restrict__ dst,
                          const int* __restrict__ rowptr, int* __restrict__ cursor,
                          int* __restrict__ csr, int E) {
  int e = blockIdx.x * 256 + threadIdx.x;
  if (e < E) {
    int d = dst[e];
    int pos = atomicAdd(&cursor[d], 1);
    csr[rowptr[d] + pos] = src[e];
  }
}

// ---------- per-dst online-softmax attention aggregate ----------
// one wave per dst node; lane l owns channels (2l, 2l+1); head = l>>4
// batched-4, software-pipelined gathers; tail masked with -1e30 scores
__global__ __launch_bounds__(256) void k_attn(
    const float* __restrict__ x, const unsigned* __restrict__ xlp,
    const unsigned* __restrict__ xrp, const float* __restrict__ att,
    const float* __restrict__ gbias, const int* __restrict__ rowptr,
    const int* __restrict__ csr, float* __restrict__ x2, int n)
{
  const int d = (int)((blockIdx.x * blockDim.x + threadIdx.x) >> 6);
  if (d >= n) return;
  const int l = threadIdx.x & 63;
  const unsigned xr = xrp[(size_t)d * 64 + l];
  const float xr0 = unpk_lo(xr), xr1 = unpk_hi(xr);
  const float2 at = ((const float2*)att)[l];
  const int beg = rowptr[d], end = rowptr[d + 1];
  const int cnt = end - beg;

  // self loop seeds the running state
  float m, s, acc0, acc1;
  {
    const unsigned xs = xlp[(size_t)d * 64 + l];
    const float a0 = unpk_lo(xs), a1 = unpk_hi(xs);
    float e0 = a0 + xr0; e0 = (e0 > 0.f) ? e0 : 0.2f * e0;
    float e1 = a1 + xr1; e1 = (e1 > 0.f) ? e1 : 0.2f * e1;
    float tt = e0 * at.x + e1 * at.y;
    tt += __shfl_xor(tt, 1); tt += __shfl_xor(tt, 2);
    tt += __shfl_xor(tt, 4); tt += __shfl_xor(tt, 8);
    m = tt; s = 1.f; acc0 = a0; acc1 = a1;
  }

  unsigned pxs[4];
  if (cnt > 0) {
    int idx[4];
    #pragma unroll
    for (int i = 0; i < 4; ++i) idx[i] = (i < cnt) ? csr[beg + i] : d;
    #pragma unroll
    for (int i = 0; i < 4; ++i) pxs[i] = xlp[(size_t)idx[i] * 64 + l];
  }
  for (int b = 0; b < cnt; b += 4) {
    unsigned xs[4];
    #pragma unroll
    for (int i = 0; i < 4; ++i) xs[i] = pxs[i];
    if (b + 4 < cnt) {    // prefetch next batch while computing this one
      int idx[4];
      #pragma unroll
      for (int i = 0; i < 4; ++i) idx[i] = (b + 4 + i < cnt) ? csr[beg + b + 4 + i] : d;
      #pragma unroll
      for (int i = 0; i < 4; ++i) pxs[i] = xlp[(size_t)idx[i] * 64 + l];
    }
    const int rem = cnt - b;
    float A0[4], A1[4], T[4];
    #pragma unroll
    for (int i = 0; i < 4; ++i) {
      A0[i] = unpk_lo(xs[i]); A1[i] = unpk_hi(xs[i]);
      float e0 = A0[i] + xr0; e0 = (e0 > 0.f) ? e0 : 0.2f * e0;
      float e1 = A1[i] + xr1; e1 = (e1 > 0.f) ? e1 : 0.2f * e1;
      T[i] = e0 * at.x + e1 * at.y;
    }
    #pragma unroll
    for (int off = 1; off < 16; off <<= 1)
      #pragma unroll
      for (int i = 0; i < 4; ++i) T[i] += __shfl_xor(T[i], off);
    #pragma unroll
    for (int i = 0; i < 4; ++i) if (i >= rem) T[i] = -1e30f;
    // batch-local softmax then one merge into running state
    const float bm = fmaxf(fmaxf(T[0], T[1]), fmaxf(T[2], T[3]));
    const float p0 = __expf(T[0] - bm), p1 = __expf(T[1] - bm);
    const float p2 = __expf(T[2] - bm), p3 = __expf(T[3] - bm);
    const float bs = p0 + p1 + p2 + p3;
    const float b0 = p0 * A0[0] + p1 * A0[1] + p2 * A0[2] + p3 * A0[3];
    const float b1 = p0 * A1[0] + p1 * A1[1] + p2 * A1[2] + p3 * A1[3];
    const float nm = fmaxf(m, bm);
    const float sc = __expf(m - nm), sb = __expf(bm - nm);
    s    = s    * sc + bs * sb;
    acc0 = acc0 * sc + b0 * sb;
    acc1 = acc1 * sc + b1 * sb;
    m = nm;
  }

  const float inv = 1.0f / s;
  const float2 xv = ((const float2*)x)[(size_t)d * 64 + l];
  const float2 gb = ((const float2*)gbias)[l];
  float2 o;
  o.x = xv.x + acc0 * inv + gb.x;
  o.y = xv.y + acc1 * inv + gb.y;
  ((float2*)x2)[(size_t)d * 64 + l] = o;
}

// ---------- fused LN2 + MFMA MLP (fc -> gelu -> proj) + residual ----------
__global__ __launch_bounds__(256, 2) void k_mlp(
    const float* __restrict__ x2, const float* __restrict__ ln2w,
    const unsigned short* __restrict__ Wfc_t, const unsigned short* __restrict__ Wpj_t,
    float* __restrict__ out, int n)
{
  __shared__ __align__(16) unsigned short sm[32768];   // 64 KB
  const int t = threadIdx.x;
  const int lane = t & 63, w = t >> 6;
  const int r0 = blockIdx.x * 64;

  { // LN2 -> swizzled bf16 h2[64][128]
    const int row = t >> 2, seg = t & 3;
    const int gr = r0 + row;
    const float4* xr4 = (const float4*)(x2 + (size_t)(gr < n ? gr : 0) * 128) + seg * 8;
    float4 v[8];
    #pragma unroll
    for (int j = 0; j < 8; ++j) v[j] = (gr < n) ? xr4[j] : make_float4(0.f,0.f,0.f,0.f);
    float s = 0.f;
    #pragma unroll
    for (int j = 0; j < 8; ++j) s += v[j].x + v[j].y + v[j].z + v[j].w;
    s += __shfl_xor(s, 1); s += __shfl_xor(s, 2);
    const float mean = s * (1.0f / 128.0f);
    float vv = 0.f;
    #pragma unroll
    for (int j = 0; j < 8; ++j) {
      float a = v[j].x - mean, b = v[j].y - mean, c = v[j].z - mean, d = v[j].w - mean;
      vv += a * a + b * b + c * c + d * d;
    }
    vv += __shfl_xor(vv, 1); vv += __shfl_xor(vv, 2);
    const float rstd = rsqrtf(vv * (1.0f / 128.0f) + 1e-5f);
    #pragma unroll
    for (int j2 = 0; j2 < 4; ++j2) {
      float4 wa = ((const float4*)ln2w)[seg * 8 + 2 * j2];
      float4 wb = ((const float4*)ln2w)[seg * 8 + 2 * j2 + 1];
      const float4 va = v[2 * j2], vb = v[2 * j2 + 1];
      uint4 pk;
      pk.x = packbf((va.x - mean) * rstd * wa.x, (va.y - mean) * rstd * wa.y);
      pk.y = packbf((va.z - mean) * rstd * wa.z, (va.w - mean) * rstd * wa.w);
      pk.z = packbf((vb.x - mean) * rstd * wb.x, (vb.y - mean) * rstd * wb.y);
      pk.w = packbf((vb.z - mean) * rstd * wb.z, (vb.w - mean) * rstd * wb.w);
      int byteoff = (row * 256 + (seg * 4 + j2) * 16) ^ ((row & 7) << 4);
      *(uint4*)((char*)sm + byteoff) = pk;
    }
  }
  __syncthreads();

  const int l15 = lane & 15, lg = lane >> 4;

  // GEMM1: out1[64][512] = h2 @ Wfc ; wave w -> cols w*128..+127
  f32x4 acc[4][8];
  #pragma unroll
  for (int m = 0; m < 4; ++m)
    #pragma unroll
    for (int nf = 0; nf < 8; ++nf) acc[m][nf] = (f32x4){0.f, 0.f, 0.f, 0.f};

  #pragma unroll
  for (int ks = 0; ks < 4; ++ks) {
    bf16x8 b[8];
    #pragma unroll
    for (int nf = 0; nf < 8; ++nf) {
      const int c = w * 128 + nf * 16 + l15;
      b[nf] = *(const bf16x8*)(Wfc_t + (size_t)c * 128 + ks * 32 + lg * 8);
    }
    bf16x8 a[4];
    #pragma unroll
    for (int m = 0; m < 4; ++m) {
      const int row = m * 16 + l15;
      const int byteoff = (row * 256 + ks * 64 + lg * 16) ^ ((row & 7) << 4);
      a[m] = *(const bf16x8*)((const char*)sm + byteoff);
    }
    #pragma unroll
    for (int m = 0; m < 4; ++m)
      #pragma unroll
      for (int nf = 0; nf < 8; ++nf)
        acc[m][nf] = __builtin_amdgcn_mfma_f32_16x16x32_bf16(a[m], b[nf], acc[m][nf], 0, 0, 0);
  }
  __syncthreads();   // h2 reads done; reuse sm as g[64][512] bf16 (swizzled)

  #pragma unroll
  for (int m = 0; m < 4; ++m)
    #pragma unroll
    for (int nf = 0; nf < 8; ++nf)
      #pragma unroll
      for (int r = 0; r < 4; ++r) {
        const int row = m * 16 + lg * 4 + r;
        const int col = w * 128 + nf * 16 + l15;
        const int byteoff = (row * 1024 + col * 2) ^ ((row & 7) << 4);
        *(unsigned short*)((char*)sm + byteoff) = (unsigned short)bf16b(gelu_f(acc[m][nf][r]));
      }
  __syncthreads();

  // GEMM2: out2[64][128] = g @ Wpj ; wave w -> cols w*32..+31
  f32x4 acc2[4][2];
  #pragma unroll
  for (int m = 0; m < 4; ++m) {
    acc2[m][0] = (f32x4){0.f, 0.f, 0.f, 0.f};
    acc2[m][1] = (f32x4){0.f, 0.f, 0.f, 0.f};
  }
  #pragma unroll 4
  for (int ks = 0; ks < 16; ++ks) {
    bf16x8 b2[2];
    #pragma unroll
    for (int nf = 0; nf < 2; ++nf) {
      const int c = w * 32 + nf * 16 + l15;
      b2[nf] = *(const bf16x8*)(Wpj_t + (size_t)c * 512 + ks * 32 + lg * 8);
    }
    bf16x8 a2[4];
    #pragma unroll
    for (int m = 0; m < 4; ++m) {
      const int row = m * 16 + l15;
      const int byteoff = (row * 1024 + ks * 64 + lg * 16) ^ ((row & 7) << 4);
      a2[m] = *(const bf16x8*)((const char*)sm + byteoff);
    }
    #pragma unroll
    for (int m = 0; m < 4; ++m) {
      acc2[m][0] = __builtin_amdgcn_mfma_f32_16x16x32_bf16(a2[m], b2[0], acc2[m][0], 0, 0, 0);
      acc2[m][1] = __builtin_amdgcn_mfma_f32_16x16x32_bf16(a2[m], b2[1], acc2[m][1], 0, 0, 0);
    }
  }

  // residual epilogue
  #pragma unroll
  for (int m = 0; m < 4; ++m)
    #pragma unroll
    for (int nf = 0; nf < 2; ++nf) {
      const int col = w * 32 + nf * 16 + l15;
      #pragma unroll
      for (int r = 0; r < 4; ++r) {
        const int gr = r0 + m * 16 + lg * 4 + r;
        if (gr < n)
          out[(size_t)gr * 128 + col] = x2[(size_t)gr * 128 + col] + acc2[m][nf][r];
      }
    }
}

// ---------- launch ----------
extern "C" void kernel_launch(void* const* d_in, const int* in_sizes, int n_in,
                              void* d_out, int out_size, void* d_ws, size_t ws_size,
                              hipStream_t stream)
{
  (void)n_in; (void)out_size; (void)ws_size;
  const float* x     = (const float*)d_in[0];
  const int*   ei    = (const int*)d_in[1];
  const float* ln1w  = (const float*)d_in[2];
  const float* Wl    = (const float*)d_in[3];
  const float* bl    = (const float*)d_in[4];
  const float* Wr    = (const float*)d_in[5];
  const float* br    = (const float*)d_in[6];
  const float* att   = (const float*)d_in[7];
  const float* gbias = (const float*)d_in[8];
  const float* ln2w  = (const float*)d_in[9];
  const float* Wfc   = (const float*)d_in[10];
  const float* Wpj   = (const float*)d_in[11];
  float* out = (float*)d_out;

  const int n = in_sizes[0] / 128;
  const int E = in_sizes[1] / 2;
  const int nb = (n + 255) / 256;

  char* w = (char*)d_ws;
  unsigned short* xl16 = (unsigned short*)w; w += (size_t)n * 128 * 2;
  unsigned short* xr16 = (unsigned short*)w; w += (size_t)n * 128 * 2;
  float*    x2  = (float*)w;    w += (size_t)n * 128 * 4;
  int*      deg = (int*)w;      w += (size_t)n * 4;
  int*   rowptr = (int*)w;      w += (size_t)(n + 1) * 4;
  int*   cursor = (int*)w;      w += (size_t)n * 4;
  int*     bsum = (int*)w;      w += 1024 * 4;
  int*      csr = (int*)w;      w += (size_t)E * 4;
  unsigned short* Wl_t  = (unsigned short*)w; w += 128 * 128 * 2;
  unsigned short* Wr_t  = (unsigned short*)w; w += 128 * 128 * 2;
  unsigned short* Wfc_t = (unsigned short*)w; w += 512 * 128 * 2;
  unsigned short* Wpj_t = (unsigned short*)w; w += 128 * 512 * 2;

  hipMemsetAsync(deg, 0, (size_t)n * 4, stream);
  hipMemsetAsync(cursor, 0, (size_t)n * 4, stream);

  k_cvt<<<(128 * 128 + 255) / 256, 256, 0, stream>>>(Wl,  Wl_t,  7, 128, 128 * 128);
  k_cvt<<<(128 * 128 + 255) / 256, 256, 0, stream>>>(Wr,  Wr_t,  7, 128, 128 * 128);
  k_cvt<<<(512 * 128 + 255) / 256, 256, 0, stream>>>(Wfc, Wfc_t, 7, 512, 512 * 128);
  k_cvt<<<(512 * 128 + 255) / 256, 256, 0, stream>>>(Wpj, Wpj_t, 9, 128, 512 * 128);

  k_gemlr<<<(n + 63) / 64, 256, 0, stream>>>(x, ln1w, Wl_t, bl, Wr_t, br, xl16, xr16, n);
  k_hist<<<(E + 255) / 256, 256, 0, stream>>>(ei + E, deg, E);
  k_scan1<<<nb, 256, 0, stream>>>(deg, bsum, n);
  k_scan2<<<1, 1024, 0, stream>>>(bsum, nb, rowptr, n, E);
  k_scan3<<<nb, 256, 0, stream>>>(deg, bsum, rowptr, n);
  k_scatter<<<(E + 255) / 256, 256, 0, stream>>>(ei, ei + E, rowptr, cursor, csr, E);
  k_attn<<<(n + 3) / 4, 256, 0, stream>>>(x, (const unsigned*)xl16, (const unsigned*)xr16,
                                          att, gbias, rowptr, csr, x2, n);
  k_mlp<<<(n + 63) / 64, 256, 0, stream>>>(x2, ln2w, Wfc_t, Wpj_t, out, n);
}

// Round 4
// 360.012 us; speedup vs baseline: 1.7958x; 1.0740x over previous
//
#include <hip/hip_runtime.h>
#include <math.h>

typedef __attribute__((ext_vector_type(8))) short bf16x8;
typedef __attribute__((ext_vector_type(4))) float f32x4;

// ---------- helpers ----------
__device__ __forceinline__ unsigned bf16b(float f) {
  unsigned u = __float_as_uint(f);
  return (u + 0x7fffu + ((u >> 16) & 1u)) >> 16;   // RNE
}
__device__ __forceinline__ unsigned packbf(float lo, float hi) {
  return bf16b(lo) | (bf16b(hi) << 16);
}
__device__ __forceinline__ float unpk_lo(unsigned u) { return __uint_as_float(u << 16); }
__device__ __forceinline__ float unpk_hi(unsigned u) { return __uint_as_float(u & 0xffff0000u); }
__device__ __forceinline__ float gelu_f(float v) {
  return 0.5f * v * (1.0f + erff(v * 0.70710678118654752f));
}

// ---------- weight transpose + bf16 convert: dst[c*K + k] = bf16(src[k*C + c]) ----------
__global__ void k_cvt(const float* __restrict__ src, unsigned short* __restrict__ dst,
                      int lgK, int C, int total) {
  int i = blockIdx.x * 256 + threadIdx.x;
  if (i < total) {
    int k = i & ((1 << lgK) - 1);
    int c = i >> lgK;
    dst[i] = (unsigned short)bf16b(src[(size_t)k * C + c]);
  }
}

// ---------- fused LN1 + [Wl|Wr] MFMA GEMM -> bf16 xl/xr ----------
__global__ __launch_bounds__(256, 2) void k_gemlr(
    const float* __restrict__ x, const float* __restrict__ ln1w,
    const unsigned short* __restrict__ Wl_t, const float* __restrict__ bl,
    const unsigned short* __restrict__ Wr_t, const float* __restrict__ br,
    unsigned short* __restrict__ xl16, unsigned short* __restrict__ xr16, int n)
{
  __shared__ __align__(16) unsigned short hs[64 * 128];   // 16 KB, swizzled bf16
  const int t = threadIdx.x;
  const int lane = t & 63, w = t >> 6;
  const int r0 = blockIdx.x * 64;

  { // LN1: 4 threads per row, 32 cols each
    const int row = t >> 2, seg = t & 3;
    const int gr = r0 + row;
    const float4* xr4 = (const float4*)(x + (size_t)(gr < n ? gr : 0) * 128) + seg * 8;
    float4 v[8];
    #pragma unroll
    for (int j = 0; j < 8; ++j) v[j] = (gr < n) ? xr4[j] : make_float4(0.f,0.f,0.f,0.f);
    float s = 0.f;
    #pragma unroll
    for (int j = 0; j < 8; ++j) s += v[j].x + v[j].y + v[j].z + v[j].w;
    s += __shfl_xor(s, 1); s += __shfl_xor(s, 2);
    const float mean = s * (1.0f / 128.0f);
    float vv = 0.f;
    #pragma unroll
    for (int j = 0; j < 8; ++j) {
      float a = v[j].x - mean, b = v[j].y - mean, c = v[j].z - mean, d = v[j].w - mean;
      vv += a * a + b * b + c * c + d * d;
    }
    vv += __shfl_xor(vv, 1); vv += __shfl_xor(vv, 2);
    const float rstd = rsqrtf(vv * (1.0f / 128.0f) + 1e-5f);
    #pragma unroll
    for (int j2 = 0; j2 < 4; ++j2) {
      float4 wa = ((const float4*)ln1w)[seg * 8 + 2 * j2];
      float4 wb = ((const float4*)ln1w)[seg * 8 + 2 * j2 + 1];
      const float4 va = v[2 * j2], vb = v[2 * j2 + 1];
      uint4 pk;
      pk.x = packbf((va.x - mean) * rstd * wa.x, (va.y - mean) * rstd * wa.y);
      pk.y = packbf((va.z - mean) * rstd * wa.z, (va.w - mean) * rstd * wa.w);
      pk.z = packbf((vb.x - mean) * rstd * wb.x, (vb.y - mean) * rstd * wb.y);
      pk.w = packbf((vb.z - mean) * rstd * wb.z, (vb.w - mean) * rstd * wb.w);
      int byteoff = (row * 256 + (seg * 4 + j2) * 16) ^ ((row & 7) << 4);
      *(uint4*)((char*)hs + byteoff) = pk;
    }
  }
  __syncthreads();

  const int l15 = lane & 15, lg = lane >> 4;
  const unsigned short* __restrict__ Wt = (w < 2) ? Wl_t : Wr_t;
  const float* __restrict__ bias = (w < 2) ? bl : br;
  unsigned short* __restrict__ outp = (w < 2) ? xl16 : xr16;
  const int cbase = (w & 1) * 64;

  f32x4 acc[4][4];
  #pragma unroll
  for (int m = 0; m < 4; ++m)
    #pragma unroll
    for (int nf = 0; nf < 4; ++nf) acc[m][nf] = (f32x4){0.f, 0.f, 0.f, 0.f};

  #pragma unroll
  for (int ks = 0; ks < 4; ++ks) {
    bf16x8 b[4];
    #pragma unroll
    for (int nf = 0; nf < 4; ++nf) {
      const int c = cbase + nf * 16 + l15;
      b[nf] = *(const bf16x8*)(Wt + (size_t)c * 128 + ks * 32 + lg * 8);
    }
    bf16x8 a[4];
    #pragma unroll
    for (int m = 0; m < 4; ++m) {
      const int row = m * 16 + l15;
      const int byteoff = (row * 256 + ks * 64 + lg * 16) ^ ((row & 7) << 4);
      a[m] = *(const bf16x8*)((const char*)hs + byteoff);
    }
    #pragma unroll
    for (int m = 0; m < 4; ++m)
      #pragma unroll
      for (int nf = 0; nf < 4; ++nf)
        acc[m][nf] = __builtin_amdgcn_mfma_f32_16x16x32_bf16(a[m], b[nf], acc[m][nf], 0, 0, 0);
  }

  #pragma unroll
  for (int nf = 0; nf < 4; ++nf) {
    const int c = cbase + nf * 16 + l15;
    const float bv = bias[c];
    #pragma unroll
    for (int m = 0; m < 4; ++m) {
      #pragma unroll
      for (int r = 0; r < 4; ++r) {
        const int gr = r0 + m * 16 + lg * 4 + r;
        if (gr < n)
          outp[(size_t)gr * 128 + c] = (unsigned short)bf16b(acc[m][nf][r] + bv);
      }
    }
  }
}

// ---------- CSR build ----------
__global__ void k_hist(const int* __restrict__ dst, int* __restrict__ deg, int E) {
  int e = blockIdx.x * 256 + threadIdx.x;
  if (e < E) atomicAdd(&deg[dst[e]], 1);
}

// per-block sums
__global__ void k_scan1(const int* __restrict__ deg, int* __restrict__ bsum, int n) {
  __shared__ int red[4];
  const int t = threadIdx.x, lane = t & 63, w = t >> 6;
  const int i = blockIdx.x * 256 + t;
  int v = (i < n) ? deg[i] : 0;
  #pragma unroll
  for (int off = 1; off < 64; off <<= 1) v += __shfl_xor(v, off);
  if (lane == 0) red[w] = v;
  __syncthreads();
  if (t == 0) bsum[blockIdx.x] = red[0] + red[1] + red[2] + red[3];
}

// exclusive scan of block sums (nb <= 1024), in place; also rowptr[n] = E
__global__ void k_scan2(int* __restrict__ bsum, int nb, int* __restrict__ rowptr,
                        int n, int Etot) {
  __shared__ int wsum[16];
  const int t = threadIdx.x, lane = t & 63, w = t >> 6;
  const int v = (t < nb) ? bsum[t] : 0;
  int incl = v;
  #pragma unroll
  for (int off = 1; off < 64; off <<= 1) {
    int u = __shfl_up(incl, off);
    if (lane >= off) incl += u;
  }
  if (lane == 63) wsum[w] = incl;
  __syncthreads();
  if (w == 0 && lane < 16) {
    int sv = wsum[lane];
    int si = sv;
    #pragma unroll
    for (int off = 1; off < 16; off <<= 1) {
      int u = __shfl_up(si, off);
      if (lane >= off) si += u;
    }
    wsum[lane] = si - sv;
  }
  __syncthreads();
  if (t < nb) bsum[t] = wsum[w] + incl - v;
  if (t == 0) rowptr[n] = Etot;
}

// per-block exclusive scan + block offset -> rowptr
__global__ void k_scan3(const int* __restrict__ deg, const int* __restrict__ bsum,
                        int* __restrict__ rowptr, int n) {
  __shared__ int ws4[4];
  const int t = threadIdx.x, lane = t & 63, w = t >> 6;
  const int i = blockIdx.x * 256 + t;
  const int v = (i < n) ? deg[i] : 0;
  int incl = v;
  #pragma unroll
  for (int off = 1; off < 64; off <<= 1) {
    int u = __shfl_up(incl, off);
    if (lane >= off) incl += u;
  }
  if (lane == 63) ws4[w] = incl;
  __syncthreads();
  if (t == 0) {
    int s1 = ws4[0], s2 = s1 + ws4[1], s3 = s2 + ws4[2];
    ws4[0] = 0; ws4[1] = s1; ws4[2] = s2; ws4[3] = s3;
  }
  __syncthreads();
  if (i < n) rowptr[i] = bsum[blockIdx.x] + ws4[w] + incl - v;
}

__global__ void k_scatter(const int* __restrict__ src, const int* __restrict__ dst,
                          const int* __restrict__ rowptr, int* __restrict__ cursor,
                          int* __restrict__ csr, int E) {
  int e = blockIdx.x * 256 + threadIdx.x;
  if (e < E) {
    int d = dst[e];
    int pos = atomicAdd(&cursor[d], 1);
    csr[rowptr[d] + pos] = src[e];
  }
}

// ---------- per-dst online-softmax attention aggregate ----------
// one wave per dst node; lane l owns channels (2l, 2l+1); head = l>>4
// batched-4, software-pipelined gathers; tail masked with -1e30 scores
__global__ __launch_bounds__(256) void k_attn(
    const float* __restrict__ x, const unsigned* __restrict__ xlp,
    const unsigned* __restrict__ xrp, const float* __restrict__ att,
    const float* __restrict__ gbias, const int* __restrict__ rowptr,
    const int* __restrict__ csr, float* __restrict__ x2, int n)
{
  const int d = (int)((blockIdx.x * blockDim.x + threadIdx.x) >> 6);
  if (d >= n) return;
  const int l = threadIdx.x & 63;
  const unsigned xr = xrp[(size_t)d * 64 + l];
  const float xr0 = unpk_lo(xr), xr1 = unpk_hi(xr);
  const float2 at = ((const float2*)att)[l];
  const int beg = rowptr[d], end = rowptr[d + 1];
  const int cnt = end - beg;

  // self loop seeds the running state
  float m, s, acc0, acc1;
  {
    const unsigned xs = xlp[(size_t)d * 64 + l];
    const float a0 = unpk_lo(xs), a1 = unpk_hi(xs);
    float e0 = a0 + xr0; e0 = (e0 > 0.f) ? e0 : 0.2f * e0;
    float e1 = a1 + xr1; e1 = (e1 > 0.f) ? e1 : 0.2f * e1;
    float tt = e0 * at.x + e1 * at.y;
    tt += __shfl_xor(tt, 1); tt += __shfl_xor(tt, 2);
    tt += __shfl_xor(tt, 4); tt += __shfl_xor(tt, 8);
    m = tt; s = 1.f; acc0 = a0; acc1 = a1;
  }

  unsigned pxs[4];
  if (cnt > 0) {
    int idx[4];
    #pragma unroll
    for (int i = 0; i < 4; ++i) idx[i] = (i < cnt) ? csr[beg + i] : d;
    #pragma unroll
    for (int i = 0; i < 4; ++i) pxs[i] = xlp[(size_t)idx[i] * 64 + l];
  }
  for (int b = 0; b < cnt; b += 4) {
    unsigned xs[4];
    #pragma unroll
    for (int i = 0; i < 4; ++i) xs[i] = pxs[i];
    if (b + 4 < cnt) {    // prefetch next batch while computing this one
      int idx[4];
      #pragma unroll
      for (int i = 0; i < 4; ++i) idx[i] = (b + 4 + i < cnt) ? csr[beg + b + 4 + i] : d;
      #pragma unroll
      for (int i = 0; i < 4; ++i) pxs[i] = xlp[(size_t)idx[i] * 64 + l];
    }
    const int rem = cnt - b;
    float A0[4], A1[4], T[4];
    #pragma unroll
    for (int i = 0; i < 4; ++i) {
      A0[i] = unpk_lo(xs[i]); A1[i] = unpk_hi(xs[i]);
      float e0 = A0[i] + xr0; e0 = (e0 > 0.f) ? e0 : 0.2f * e0;
      float e1 = A1[i] + xr1; e1 = (e1 > 0.f) ? e1 : 0.2f * e1;
      T[i] = e0 * at.x + e1 * at.y;
    }
    #pragma unroll
    for (int off = 1; off < 16; off <<= 1)
      #pragma unroll
      for (int i = 0; i < 4; ++i) T[i] += __shfl_xor(T[i], off);
    #pragma unroll
    for (int i = 0; i < 4; ++i) if (i >= rem) T[i] = -1e30f;
    // batch-local softmax then one merge into running state
    const float bm = fmaxf(fmaxf(T[0], T[1]), fmaxf(T[2], T[3]));
    const float p0 = __expf(T[0] - bm), p1 = __expf(T[1] - bm);
    const float p2 = __expf(T[2] - bm), p3 = __expf(T[3] - bm);
    const float bs = p0 + p1 + p2 + p3;
    const float b0 = p0 * A0[0] + p1 * A0[1] + p2 * A0[2] + p3 * A0[3];
    const float b1 = p0 * A1[0] + p1 * A1[1] + p2 * A1[2] + p3 * A1[3];
    const float nm = fmaxf(m, bm);
    const float sc = __expf(m - nm), sb = __expf(bm - nm);
    s    = s    * sc + bs * sb;
    acc0 = acc0 * sc + b0 * sb;
    acc1 = acc1 * sc + b1 * sb;
    m = nm;
  }

  const float inv = 1.0f / s;
  const float2 xv = ((const float2*)x)[(size_t)d * 64 + l];
  const float2 gb = ((const float2*)gbias)[l];
  float2 o;
  o.x = xv.x + acc0 * inv + gb.x;
  o.y = xv.y + acc1 * inv + gb.y;
  ((float2*)x2)[(size_t)d * 64 + l] = o;
}

// ---------- fused LN2 + MFMA MLP (fc -> gelu -> proj) + residual ----------
// BM=32 rows/block, 32 KB LDS (gelu buffer aliases h2), 4 blocks/CU target
__global__ __launch_bounds__(256, 4) void k_mlp(
    const float* __restrict__ x2, const float* __restrict__ ln2w,
    const unsigned short* __restrict__ Wfc_t, const unsigned short* __restrict__ Wpj_t,
    float* __restrict__ out, int n)
{
  __shared__ __align__(16) unsigned short sm[16384];   // 32 KB: h2[32][128] then g[32][512]
  const int t = threadIdx.x;
  const int lane = t & 63, w = t >> 6;
  const int r0 = blockIdx.x * 32;
  const int l15 = lane & 15, lg = lane >> 4;

  { // LN2: 8 threads per row, 16 cols each -> swizzled bf16 h2[32][128]
    const int row = t >> 3, seg = t & 7;
    const int gr = r0 + row;
    const float4* xr4 = (const float4*)(x2 + (size_t)(gr < n ? gr : 0) * 128) + seg * 4;
    float4 v[4];
    #pragma unroll
    for (int j = 0; j < 4; ++j) v[j] = (gr < n) ? xr4[j] : make_float4(0.f,0.f,0.f,0.f);
    float s = 0.f;
    #pragma unroll
    for (int j = 0; j < 4; ++j) s += v[j].x + v[j].y + v[j].z + v[j].w;
    s += __shfl_xor(s, 1); s += __shfl_xor(s, 2); s += __shfl_xor(s, 4);
    const float mean = s * (1.0f / 128.0f);
    float vv = 0.f;
    #pragma unroll
    for (int j = 0; j < 4; ++j) {
      float a = v[j].x - mean, b = v[j].y - mean, c = v[j].z - mean, d = v[j].w - mean;
      vv += a * a + b * b + c * c + d * d;
    }
    vv += __shfl_xor(vv, 1); vv += __shfl_xor(vv, 2); vv += __shfl_xor(vv, 4);
    const float rstd = rsqrtf(vv * (1.0f / 128.0f) + 1e-5f);
    #pragma unroll
    for (int j2 = 0; j2 < 2; ++j2) {
      float4 wa = ((const float4*)ln2w)[seg * 4 + 2 * j2];
      float4 wb = ((const float4*)ln2w)[seg * 4 + 2 * j2 + 1];
      const float4 va = v[2 * j2], vb = v[2 * j2 + 1];
      uint4 pk;
      pk.x = packbf((va.x - mean) * rstd * wa.x, (va.y - mean) * rstd * wa.y);
      pk.y = packbf((va.z - mean) * rstd * wa.z, (va.w - mean) * rstd * wa.w);
      pk.z = packbf((vb.x - mean) * rstd * wb.x, (vb.y - mean) * rstd * wb.y);
      pk.w = packbf((vb.z - mean) * rstd * wb.z, (vb.w - mean) * rstd * wb.w);
      int byteoff = (row * 256 + seg * 32 + j2 * 16) ^ ((row & 7) << 4);
      *(uint4*)((char*)sm + byteoff) = pk;
    }
  }

  // prefetch GEMM1 ks=0 weight fragments BEFORE the barrier (hides L2 latency)
  bf16x8 bpre[8];
  #pragma unroll
  for (int nf = 0; nf < 8; ++nf) {
    const int c = w * 128 + nf * 16 + l15;
    bpre[nf] = *(const bf16x8*)(Wfc_t + (size_t)c * 128 + lg * 8);
  }
  __syncthreads();

  // GEMM1: out1[32][512] = h2 @ Wfc ; wave w -> cols w*128..+127
  f32x4 acc[2][8];
  #pragma unroll
  for (int m = 0; m < 2; ++m)
    #pragma unroll
    for (int nf = 0; nf < 8; ++nf) acc[m][nf] = (f32x4){0.f, 0.f, 0.f, 0.f};

  #pragma unroll
  for (int ks = 0; ks < 4; ++ks) {
    bf16x8 b[8];
    #pragma unroll
    for (int nf = 0; nf < 8; ++nf) {
      if (ks == 0) b[nf] = bpre[nf];
      else {
        const int c = w * 128 + nf * 16 + l15;
        b[nf] = *(const bf16x8*)(Wfc_t + (size_t)c * 128 + ks * 32 + lg * 8);
      }
    }
    bf16x8 a[2];
    #pragma unroll
    for (int m = 0; m < 2; ++m) {
      const int row = m * 16 + l15;
      const int byteoff = (row * 256 + ks * 64 + lg * 16) ^ ((row & 7) << 4);
      a[m] = *(const bf16x8*)((const char*)sm + byteoff);
    }
    #pragma unroll
    for (int m = 0; m < 2; ++m)
      #pragma unroll
      for (int nf = 0; nf < 8; ++nf)
        acc[m][nf] = __builtin_amdgcn_mfma_f32_16x16x32_bf16(a[m], b[nf], acc[m][nf], 0, 0, 0);
  }

  // prefetch GEMM2 ks=0 weight fragments (independent of LDS) under gelu
  bf16x8 b2pre[2];
  #pragma unroll
  for (int nf = 0; nf < 2; ++nf) {
    const int c = w * 32 + nf * 16 + l15;
    b2pre[nf] = *(const bf16x8*)(Wpj_t + (size_t)c * 512 + lg * 8);
  }
  __syncthreads();   // h2 reads done; reuse sm as g[32][512] bf16 (swizzled)

  #pragma unroll
  for (int m = 0; m < 2; ++m)
    #pragma unroll
    for (int nf = 0; nf < 8; ++nf)
      #pragma unroll
      for (int r = 0; r < 4; ++r) {
        const int row = m * 16 + lg * 4 + r;
        const int col = w * 128 + nf * 16 + l15;
        const int byteoff = (row * 1024 + col * 2) ^ ((row & 7) << 4);
        *(unsigned short*)((char*)sm + byteoff) = (unsigned short)bf16b(gelu_f(acc[m][nf][r]));
      }
  __syncthreads();

  // GEMM2: out2[32][128] = g @ Wpj ; wave w -> cols w*32..+31
  f32x4 acc2[2][2];
  #pragma unroll
  for (int m = 0; m < 2; ++m) {
    acc2[m][0] = (f32x4){0.f, 0.f, 0.f, 0.f};
    acc2[m][1] = (f32x4){0.f, 0.f, 0.f, 0.f};
  }
  #pragma unroll 4
  for (int ks = 0; ks < 16; ++ks) {
    bf16x8 b2[2];
    #pragma unroll
    for (int nf = 0; nf < 2; ++nf) {
      if (ks == 0) b2[nf] = b2pre[nf];
      else {
        const int c = w * 32 + nf * 16 + l15;
        b2[nf] = *(const bf16x8*)(Wpj_t + (size_t)c * 512 + ks * 32 + lg * 8);
      }
    }
    bf16x8 a2[2];
    #pragma unroll
    for (int m = 0; m < 2; ++m) {
      const int row = m * 16 + l15;
      const int byteoff = (row * 1024 + ks * 64 + lg * 16) ^ ((row & 7) << 4);
      a2[m] = *(const bf16x8*)((const char*)sm + byteoff);
    }
    #pragma unroll
    for (int m = 0; m < 2; ++m) {
      acc2[m][0] = __builtin_amdgcn_mfma_f32_16x16x32_bf16(a2[m], b2[0], acc2[m][0], 0, 0, 0);
      acc2[m][1] = __builtin_amdgcn_mfma_f32_16x16x32_bf16(a2[m], b2[1], acc2[m][1], 0, 0, 0);
    }
  }

  // residual epilogue
  #pragma unroll
  for (int m = 0; m < 2; ++m)
    #pragma unroll
    for (int nf = 0; nf < 2; ++nf) {
      const int col = w * 32 + nf * 16 + l15;
      #pragma unroll
      for (int r = 0; r < 4; ++r) {
        const int gr = r0 + m * 16 + lg * 4 + r;
        if (gr < n)
          out[(size_t)gr * 128 + col] = x2[(size_t)gr * 128 + col] + acc2[m][nf][r];
      }
    }
}

// ---------- launch ----------
extern "C" void kernel_launch(void* const* d_in, const int* in_sizes, int n_in,
                              void* d_out, int out_size, void* d_ws, size_t ws_size,
                              hipStream_t stream)
{
  (void)n_in; (void)out_size; (void)ws_size;
  const float* x     = (const float*)d_in[0];
  const int*   ei    = (const int*)d_in[1];
  const float* ln1w  = (const float*)d_in[2];
  const float* Wl    = (const float*)d_in[3];
  const float* bl    = (const float*)d_in[4];
  const float* Wr    = (const float*)d_in[5];
  const float* br    = (const float*)d_in[6];
  const float* att   = (const float*)d_in[7];
  const float* gbias = (const float*)d_in[8];
  const float* ln2w  = (const float*)d_in[9];
  const float* Wfc   = (const float*)d_in[10];
  const float* Wpj   = (const float*)d_in[11];
  float* out = (float*)d_out;

  const int n = in_sizes[0] / 128;
  const int E = in_sizes[1] / 2;
  const int nb = (n + 255) / 256;

  char* w = (char*)d_ws;
  unsigned short* xl16 = (unsigned short*)w; w += (size_t)n * 128 * 2;
  unsigned short* xr16 = (unsigned short*)w; w += (size_t)n * 128 * 2;
  float*    x2  = (float*)w;    w += (size_t)n * 128 * 4;
  int*      deg = (int*)w;      w += (size_t)n * 4;
  int*   rowptr = (int*)w;      w += (size_t)(n + 1) * 4;
  int*   cursor = (int*)w;      w += (size_t)n * 4;
  int*     bsum = (int*)w;      w += 1024 * 4;
  int*      csr = (int*)w;      w += (size_t)E * 4;
  unsigned short* Wl_t  = (unsigned short*)w; w += 128 * 128 * 2;
  unsigned short* Wr_t  = (unsigned short*)w; w += 128 * 128 * 2;
  unsigned short* Wfc_t = (unsigned short*)w; w += 512 * 128 * 2;
  unsigned short* Wpj_t = (unsigned short*)w; w += 128 * 512 * 2;

  hipMemsetAsync(deg, 0, (size_t)n * 4, stream);
  hipMemsetAsync(cursor, 0, (size_t)n * 4, stream);

  k_cvt<<<(128 * 128 + 255) / 256, 256, 0, stream>>>(Wl,  Wl_t,  7, 128, 128 * 128);
  k_cvt<<<(128 * 128 + 255) / 256, 256, 0, stream>>>(Wr,  Wr_t,  7, 128, 128 * 128);
  k_cvt<<<(512 * 128 + 255) / 256, 256, 0, stream>>>(Wfc, Wfc_t, 7, 512, 512 * 128);
  k_cvt<<<(512 * 128 + 255) / 256, 256, 0, stream>>>(Wpj, Wpj_t, 9, 128, 512 * 128);

  k_gemlr<<<(n + 63) / 64, 256, 0, stream>>>(x, ln1w, Wl_t, bl, Wr_t, br, xl16, xr16, n);
  k_hist<<<(E + 255) / 256, 256, 0, stream>>>(ei + E, deg, E);
  k_scan1<<<nb, 256, 0, stream>>>(deg, bsum, n);
  k_scan2<<<1, 1024, 0, stream>>>(bsum, nb, rowptr, n, E);
  k_scan3<<<nb, 256, 0, stream>>>(deg, bsum, rowptr, n);
  k_scatter<<<(E + 255) / 256, 256, 0, stream>>>(ei, ei + E, rowptr, cursor, csr, E);
  k_attn<<<(n + 3) / 4, 256, 0, stream>>>(x, (const unsigned*)xl16, (const unsigned*)xr16,
                                          att, gbias, rowptr, csr, x2, n);
  k_mlp<<<(n + 31) / 32, 256, 0, stream>>>(x2, ln2w, Wfc_t, Wpj_t, out, n);
}